// Round 8
// baseline (531.636 us; speedup 1.0000x reference)
//
#include <hip/hip_runtime.h>
#include <hip/hip_bf16.h>

#define NN 100000
#define NE 1600000
#define NF 128
#define NC 40
#define BN_EPS 1e-5f

#define NB 256          // bucket slots (power of 2); used: (NN+511)>>9 = 196
#define NBU ((NN + 511) >> 9)
#define PT_TILE 4096    // edges per partition tile
#define PT_GRID ((NE + PT_TILE - 1) / PT_TILE)  // 391
#define SBANK 32        // global stat-accumulator banks (conv)
#define NBANK2 64       // banks for final-BN stats
#define NTILES (NN / 16)   // 6250 row-tiles of 16, exact
#define LIN_BLKS 625       // 625 blocks x 10 contiguous tiles
#define TILES_PER_BLK 10
#define LIN80_GRID 512

typedef __attribute__((ext_vector_type(8))) short short8;
typedef __attribute__((ext_vector_type(4))) float float4v;
typedef __attribute__((ext_vector_type(4))) int int4v;

__device__ __forceinline__ unsigned short f2b(float f) {
    __hip_bfloat16 h = __float2bfloat16(f);
    return *reinterpret_cast<unsigned short*>(&h);
}
__device__ __forceinline__ float b2f_hi(unsigned u) { return __uint_as_float(u & 0xffff0000u); }
__device__ __forceinline__ float b2f_lo(unsigned u) { return __uint_as_float(u << 16); }

// ---------------- CSR build: bucket-partitioned (single-writer regions) ----------------

__global__ __launch_bounds__(256) void bhist_kernel(const int* __restrict__ dst,
                                                    int* __restrict__ bhist) {
    __shared__ int lh[NB];
    int tid = threadIdx.x;
    lh[tid] = 0;
    __syncthreads();
    int base = blockIdx.x * PT_TILE;
    int cnt = min(PT_TILE, NE - base);
    const int4v* d4 = (const int4v*)(dst + base);
    int cnt4 = cnt >> 2;
    for (int i = tid; i < cnt4; i += 256) {
        int4v d = __builtin_nontemporal_load(d4 + i);
        atomicAdd(&lh[d[0] >> 9], 1);
        atomicAdd(&lh[d[1] >> 9], 1);
        atomicAdd(&lh[d[2] >> 9], 1);
        atomicAdd(&lh[d[3] >> 9], 1);
    }
    __syncthreads();
    if (lh[tid]) atomicAdd(&bhist[tid], lh[tid]);
}

__global__ __launch_bounds__(256) void bscan_kernel(const int* __restrict__ bhist,
                                                    int* __restrict__ bbase,
                                                    int* __restrict__ bcur) {
    __shared__ int lds[NB];
    int t = threadIdx.x;
    int v = bhist[t];
    lds[t] = v;
    __syncthreads();
    for (int off = 1; off < NB; off <<= 1) {
        int u = (t >= off) ? lds[t - off] : 0;
        __syncthreads();
        lds[t] += u;
        __syncthreads();
    }
    int ex = lds[t] - v;
    bbase[t] = ex;
    bcur[t] = ex;
}

__global__ __launch_bounds__(256) void part_kernel(const int* __restrict__ src,
                                                   const int* __restrict__ dst,
                                                   int* __restrict__ bcur,
                                                   int2* __restrict__ stage) {
    __shared__ int2 pairs[PT_TILE];  // 32 KB
    __shared__ int lhist[NB];
    __shared__ int gbase[NB];
    int tid = threadIdx.x;
    int base = blockIdx.x * PT_TILE;
    int cnt = min(PT_TILE, NE - base);
    int cnt4 = cnt >> 2;

    lhist[tid] = 0;
    __syncthreads();

    const int4v* d4 = (const int4v*)(dst + base);
    const int4v* s4 = (const int4v*)(src + base);
    for (int i = tid; i < cnt4; i += 256) {
        int4v d = __builtin_nontemporal_load(d4 + i);
        int4v s = __builtin_nontemporal_load(s4 + i);
#pragma unroll
        for (int j = 0; j < 4; ++j) {
            pairs[j * cnt4 + i] = make_int2(d[j], s[j]);
            atomicAdd(&lhist[d[j] >> 9], 1);
        }
    }
    __syncthreads();

    int c = lhist[tid];
    gbase[tid] = (c > 0) ? atomicAdd(&bcur[tid], c) : 0;
    lhist[tid] = 0;
    __syncthreads();

    for (int k = tid; k < cnt; k += 256) {
        int2 p = pairs[k];
        int b = p.x >> 9;
        int pos = atomicAdd(&lhist[b], 1);
        stage[gbase[b] + pos] = p;
    }
}

// Merged deg+scan+fill: one block per bucket (R7-verified).

__global__ __launch_bounds__(512) void bucket_build_kernel(const long long* __restrict__ stage,
                                                           const int* __restrict__ bbase,
                                                           const int* __restrict__ bcur,
                                                           int* __restrict__ row_ptr,
                                                           float* __restrict__ inv_cnt,
                                                           int* __restrict__ csr) {
    __shared__ int hist[512];
    __shared__ int sa[512], sb[512];  // scan ping-pong
    __shared__ int cur[512];
    int tid = threadIdx.x;
    int b = blockIdx.x;
    int s = bbase[b], e = bcur[b];

    hist[tid] = 0;
    __syncthreads();

    for (int i = s + tid; i < e; i += 512) {
        long long p = __builtin_nontemporal_load(stage + i);
        int dl = ((int)(p & 0xffffffffLL)) & 511;
        atomicAdd(&hist[dl], 1);
    }
    __syncthreads();

    sa[tid] = hist[tid];
    __syncthreads();
    int* pin = sa;
    int* pout = sb;
    for (int off = 1; off < 512; off <<= 1) {
        pout[tid] = pin[tid] + ((tid >= off) ? pin[tid - off] : 0);
        __syncthreads();
        int* t = pin; pin = pout; pout = t;
    }

    int d = hist[tid];
    int ex = pin[tid] - d;  // exclusive
    cur[tid] = ex;
    int n = b * 512 + tid;
    if (n < NN) {
        row_ptr[n] = s + ex;
        inv_cnt[n] = 1.0f / (float)(d > 0 ? d : 1);
    }
    if (b == 0 && tid == 0) row_ptr[NN] = NE;
    __syncthreads();

    for (int i = s + tid; i < e; i += 512) {
        long long p = __builtin_nontemporal_load(stage + i);
        int dl = ((int)(p & 0xffffffffLL)) & 511;
        int sv = (int)(p >> 32);
        int pos = atomicAdd(&cur[dl], 1);
        csr[s + pos] = sv;
    }
}

// ---------------- fp32 -> bf16 bulk convert ----------------

__global__ __launch_bounds__(256) void f2b4_kernel(const float* __restrict__ in,
                                                   unsigned short* __restrict__ out, int n4) {
    int i = blockIdx.x * 256 + threadIdx.x;
    if (i < n4) {
        float4 v = ((const float4*)in)[i];
        ushort4 o;
        o.x = f2b(v.x); o.y = f2b(v.y); o.z = f2b(v.z); o.w = f2b(v.w);
        ((ushort4*)out)[i] = o;
    }
}

// ---------------- pack W into MFMA fragment order ----------------

__global__ __launch_bounds__(64) void pack_w_kernel(const float* __restrict__ Wl,
                                                    const float* __restrict__ Wr,
                                                    unsigned short* __restrict__ Bp) {
    int nt = blockIdx.x & 7;
    int kk = blockIdx.x >> 3;
    int lane = threadIdx.x;
    int n = nt * 16 + (lane & 15);
    int kb = kk * 32 + (lane >> 4) * 8;
    size_t base = ((size_t)(kk * 8 + nt) * 64 + lane) * 8;
#pragma unroll
    for (int j = 0; j < 8; ++j) {
        int k = kb + j;
        float v = (k < NF) ? Wl[(size_t)n * NF + k] : Wr[(size_t)n * NF + (k - NF)];
        Bp[base + j] = f2b(v);
    }
}

__global__ __launch_bounds__(64) void pack_w80_kernel(const float* __restrict__ Wl,
                                                      const float* __restrict__ Wr,
                                                      unsigned short* __restrict__ Bp) {
    int nt = blockIdx.x % 5;
    int kk = blockIdx.x / 5;
    int lane = threadIdx.x;
    int n = nt * 16 + (lane & 15);
    int kb = kk * 32 + (lane >> 4) * 8;
    size_t base = ((size_t)(kk * 5 + nt) * 64 + lane) * 8;
#pragma unroll
    for (int j = 0; j < 8; ++j) {
        int k = kb + j;
        float v = (n < NC) ? Wl[(size_t)n * NF + k] : Wr[(size_t)(n - NC) * NF + k];
        Bp[base + j] = f2b(v);
    }
}

// ---------------- mean aggregation: quarter-wave per node ----------------

__global__ __launch_bounds__(256) void agg_mean_bf16(const unsigned short* __restrict__ X,
                                                     const int* __restrict__ csr,
                                                     const int* __restrict__ row_ptr,
                                                     const float* __restrict__ inv_cnt,
                                                     unsigned short* __restrict__ out) {
    int tid = threadIdx.x;
    int lane = tid & 63;
    int wave = tid >> 6;
    int qw = lane >> 4;
    int sl = lane & 15;
    int n = blockIdx.x * 16 + wave * 4 + qw;
    if (n >= NN) return;
    int s = row_ptr[n], e = row_ptr[n + 1];
    int foff = sl * 8;  // feature offset (8 bf16 = 16B per lane)

    float a[8];
#pragma unroll
    for (int j = 0; j < 8; ++j) a[j] = 0.f;

    int i = s;
    for (; i + 4 <= e; i += 4) {
        int s0 = csr[i], s1 = csr[i + 1], s2 = csr[i + 2], s3 = csr[i + 3];
        uint4 u0 = *(const uint4*)(X + (size_t)s0 * NF + foff);
        uint4 u1 = *(const uint4*)(X + (size_t)s1 * NF + foff);
        uint4 u2 = *(const uint4*)(X + (size_t)s2 * NF + foff);
        uint4 u3 = *(const uint4*)(X + (size_t)s3 * NF + foff);
        a[0] += b2f_lo(u0.x) + b2f_lo(u1.x) + b2f_lo(u2.x) + b2f_lo(u3.x);
        a[1] += b2f_hi(u0.x) + b2f_hi(u1.x) + b2f_hi(u2.x) + b2f_hi(u3.x);
        a[2] += b2f_lo(u0.y) + b2f_lo(u1.y) + b2f_lo(u2.y) + b2f_lo(u3.y);
        a[3] += b2f_hi(u0.y) + b2f_hi(u1.y) + b2f_hi(u2.y) + b2f_hi(u3.y);
        a[4] += b2f_lo(u0.z) + b2f_lo(u1.z) + b2f_lo(u2.z) + b2f_lo(u3.z);
        a[5] += b2f_hi(u0.z) + b2f_hi(u1.z) + b2f_hi(u2.z) + b2f_hi(u3.z);
        a[6] += b2f_lo(u0.w) + b2f_lo(u1.w) + b2f_lo(u2.w) + b2f_lo(u3.w);
        a[7] += b2f_hi(u0.w) + b2f_hi(u1.w) + b2f_hi(u2.w) + b2f_hi(u3.w);
    }
    for (; i < e; ++i) {
        uint4 u = *(const uint4*)(X + (size_t)csr[i] * NF + foff);
        a[0] += b2f_lo(u.x); a[1] += b2f_hi(u.x);
        a[2] += b2f_lo(u.y); a[3] += b2f_hi(u.y);
        a[4] += b2f_lo(u.z); a[5] += b2f_hi(u.z);
        a[6] += b2f_lo(u.w); a[7] += b2f_hi(u.w);
    }

    float ic = inv_cnt[n];
    uint4 o;
    o.x = (unsigned)f2b(a[0] * ic) | ((unsigned)f2b(a[1] * ic) << 16);
    o.y = (unsigned)f2b(a[2] * ic) | ((unsigned)f2b(a[3] * ic) << 16);
    o.z = (unsigned)f2b(a[4] * ic) | ((unsigned)f2b(a[5] * ic) << 16);
    o.w = (unsigned)f2b(a[6] * ic) | ((unsigned)f2b(a[7] * ic) << 16);
    *(uint4*)(out + (size_t)n * NF + foff) = o;
}

// ---------------- MFMA linear (128-out, K=256), pipelined ----------------
// R2-R7 diagnosis: the allocator targets the 64-VGPR tier by SINKING every
// load to its use -> load;waitcnt(0);mfma fully serialized at ~800 cyc/load
// (~18.7K cyc/tile observed). Fix: 8 waves (wave = one nt), B panel in LDS,
// xf double-buffered in registers with sched_barrier(0) pinning next-tile
// loads BEFORE current-tile MFMAs -> compiler must emit counted vmcnt and
// keep ~8 loads in flight per wave. 625 blocks x 10 contiguous tiles.

template <bool RELU, bool STATS>
__device__ __forceinline__ void lin_body(const unsigned short* __restrict__ Ab,
                                         const unsigned short* __restrict__ Xb,
                                         const unsigned short* __restrict__ Bp,
                                         const float* __restrict__ bias,
                                         unsigned short* __restrict__ outb,
                                         float* __restrict__ sums,
                                         short8* Bs, float* ls) {
    int tid = threadIdx.x;
    int w = tid >> 6;      // wave 0..7 = output tile nt
    int lane = tid & 63;
    int quad = lane >> 4;
    int sl = lane & 15;

    const short8* Bv = (const short8*)Bp;
    for (int i = tid; i < 4096; i += 512) Bs[i] = Bv[i];  // 64 KB panel
    if (STATS && tid < 256) ls[tid] = 0.f;
    __syncthreads();

    float4 bias4 = *(const float4*)(bias + w * 16 + quad * 4);

    float sv[4], qv[4];
#pragma unroll
    for (int r = 0; r < 4; ++r) { sv[r] = 0.f; qv[r] = 0.f; }

    int tbase = blockIdx.x * TILES_PER_BLK;
    short8 xa[8], xb_[8];

    auto issue = [&](short8* buf, int t) {
        int rr = t * 16 + sl;
        const unsigned short* arow = Ab + (size_t)rr * NF;
        const unsigned short* xrow = Xb + (size_t)rr * NF;
#pragma unroll
        for (int kk = 0; kk < 8; ++kk) {
            int kb = (kk & 3) * 32 + quad * 8;
            buf[kk] = *(const short8*)(((kk < 4) ? arow : xrow) + kb);
        }
    };

    auto compute = [&](short8* buf, int t) {
        float4v acc = (float4v){0.f, 0.f, 0.f, 0.f};
#pragma unroll
        for (int kk = 0; kk < 8; ++kk) {
            short8 bfr = Bs[(kk * 8 + w) * 64 + lane];
            acc = __builtin_amdgcn_mfma_f32_16x16x32_bf16(bfr, buf[kk], acc, 0, 0, 0);
        }
        int rr = t * 16 + sl;
        int c0 = w * 16 + quad * 4;
        float v0 = acc[0] + bias4.x;
        float v1 = acc[1] + bias4.y;
        float v2 = acc[2] + bias4.z;
        float v3 = acc[3] + bias4.w;
        if (RELU) {
            v0 = fmaxf(v0, 0.f); v1 = fmaxf(v1, 0.f);
            v2 = fmaxf(v2, 0.f); v3 = fmaxf(v3, 0.f);
        }
        if (STATS) {
            sv[0] += v0; qv[0] += v0 * v0;
            sv[1] += v1; qv[1] += v1 * v1;
            sv[2] += v2; qv[2] += v2 * v2;
            sv[3] += v3; qv[3] += v3 * v3;
        }
        ushort4 o;
        o.x = f2b(v0); o.y = f2b(v1); o.z = f2b(v2); o.w = f2b(v3);
        *(ushort4*)(outb + (size_t)rr * NF + c0) = o;
    };

    issue(xa, tbase);
#pragma unroll
    for (int i = 0; i < TILES_PER_BLK; i += 2) {
        issue(xb_, tbase + i + 1);
        __builtin_amdgcn_sched_barrier(0);   // loads above may not sink past
        compute(xa, tbase + i);
        if (i + 2 < TILES_PER_BLK) issue(xa, tbase + i + 2);
        __builtin_amdgcn_sched_barrier(0);
        compute(xb_, tbase + i + 1);
    }

    if (STATS) {
        int c0 = w * 16 + quad * 4;
#pragma unroll
        for (int r = 0; r < 4; ++r) {
            atomicAdd(&ls[c0 + r], sv[r]);
            atomicAdd(&ls[128 + c0 + r], qv[r]);
        }
        __syncthreads();
        if (tid < 256) atomicAdd(&sums[(blockIdx.x & (SBANK - 1)) * 256 + tid], ls[tid]);
    }
}

__global__ __launch_bounds__(512, 4) void lin_conv1_kernel(const unsigned short* __restrict__ Ab,
                                                           const unsigned short* __restrict__ Xb,
                                                           const unsigned short* __restrict__ Bp,
                                                           const float* __restrict__ bias,
                                                           unsigned short* __restrict__ outb) {
    __shared__ short8 Bs[4096];
    lin_body<true, false>(Ab, Xb, Bp, bias, outb, nullptr, Bs, nullptr);
}

__global__ __launch_bounds__(512, 4) void lin_convx_kernel(const unsigned short* __restrict__ Ab,
                                                           const unsigned short* __restrict__ Xb,
                                                           const unsigned short* __restrict__ Bp,
                                                           const float* __restrict__ bias,
                                                           unsigned short* __restrict__ outb,
                                                           float* __restrict__ sums) {
    __shared__ short8 Bs[4096];
    __shared__ float ls[256];
    lin_body<false, true>(Ab, Xb, Bp, bias, outb, sums, Bs, ls);
}

// ---------------- BN3 coefficients: fold banked sums, scale/shift per column ----------------

__global__ __launch_bounds__(128) void bn3_coef_kernel(const float* __restrict__ sums,
                                                       const float* __restrict__ g,
                                                       const float* __restrict__ be,
                                                       float* __restrict__ sc,
                                                       float* __restrict__ sh) {
    int c = threadIdx.x;
    float sv = 0.f, qv = 0.f;
    for (int b = 0; b < SBANK; ++b) {
        sv += sums[b * 256 + c];
        qv += sums[b * 256 + 128 + c];
    }
    float invN = 1.0f / (float)NN;
    float mu = sv * invN;
    float var = qv * invN - mu * mu;
    float s = rsqrtf(var + BN_EPS) * g[c];
    sc[c] = s;
    sh[c] = be[c] - mu * s;
}

// ---------------- MFMA linear conv2 (80-out, K=128), per-wave tile stream (R7 form) ----------------

__global__ __launch_bounds__(256, 2) void lin80_mfma_kernel(const unsigned short* __restrict__ Xb,
                                                            const unsigned short* __restrict__ Bp,
                                                            const float* __restrict__ b2,
                                                            const float* __restrict__ bnsc,
                                                            const float* __restrict__ bnsh,
                                                            unsigned short* __restrict__ t40,
                                                            float* __restrict__ z40) {
    int tid = threadIdx.x;
    int wave = tid >> 6;
    int lane = tid & 63;
    int quad = lane >> 4;
    int sl = lane & 15;
    const short8* Bv = (const short8*)Bp;

    short8 bfr[4][5];
#pragma unroll
    for (int kk = 0; kk < 4; ++kk)
#pragma unroll
        for (int nt = 0; nt < 5; ++nt)
            bfr[kk][nt] = Bv[(kk * 5 + nt) * 64 + lane];

    float4 sc0[4], sc1[4], sh0[4], sh1[4];
#pragma unroll
    for (int kk = 0; kk < 4; ++kk) {
        int kb = kk * 32 + quad * 8;
        sc0[kk] = *(const float4*)(bnsc + kb);
        sc1[kk] = *(const float4*)(bnsc + kb + 4);
        sh0[kk] = *(const float4*)(bnsh + kb);
        sh1[kk] = *(const float4*)(bnsh + kb + 4);
    }

    int gw = blockIdx.x * 4 + wave;
    for (int t = gw; t < NTILES; t += LIN80_GRID * 4) {
        int rr = t * 16 + sl;
        const unsigned short* xrow = Xb + (size_t)rr * NF;

        float4v acc[5];
#pragma unroll
        for (int nt = 0; nt < 5; ++nt) acc[nt] = (float4v){0.f, 0.f, 0.f, 0.f};

#pragma unroll
        for (int kk = 0; kk < 4; ++kk) {
            uint4 u = *(const uint4*)(xrow + kk * 32 + quad * 8);
            short8 xf;
            xf[0] = (short)f2b(fmaxf(b2f_lo(u.x) * sc0[kk].x + sh0[kk].x, 0.f));
            xf[1] = (short)f2b(fmaxf(b2f_hi(u.x) * sc0[kk].y + sh0[kk].y, 0.f));
            xf[2] = (short)f2b(fmaxf(b2f_lo(u.y) * sc0[kk].z + sh0[kk].z, 0.f));
            xf[3] = (short)f2b(fmaxf(b2f_hi(u.y) * sc0[kk].w + sh0[kk].w, 0.f));
            xf[4] = (short)f2b(fmaxf(b2f_lo(u.z) * sc1[kk].x + sh1[kk].x, 0.f));
            xf[5] = (short)f2b(fmaxf(b2f_hi(u.z) * sc1[kk].y + sh1[kk].y, 0.f));
            xf[6] = (short)f2b(fmaxf(b2f_lo(u.w) * sc1[kk].z + sh1[kk].z, 0.f));
            xf[7] = (short)f2b(fmaxf(b2f_hi(u.w) * sc1[kk].w + sh1[kk].w, 0.f));
#pragma unroll
            for (int nt = 0; nt < 5; ++nt)
                acc[nt] = __builtin_amdgcn_mfma_f32_16x16x32_bf16(bfr[kk][nt], xf, acc[nt], 0, 0, 0);
        }

#pragma unroll
        for (int nt = 0; nt < 5; ++nt) {
            int c0 = nt * 16 + quad * 4;
            if (c0 < NC) {
                ushort4 o;
                o.x = f2b(acc[nt][0]); o.y = f2b(acc[nt][1]);
                o.z = f2b(acc[nt][2]); o.w = f2b(acc[nt][3]);
                *(ushort4*)(t40 + (size_t)rr * NC + c0) = o;
            } else {
                float4 bz = *(const float4*)(b2 + c0 - NC);
                float4 o;
                o.x = acc[nt][0] + bz.x; o.y = acc[nt][1] + bz.y;
                o.z = acc[nt][2] + bz.z; o.w = acc[nt][3] + bz.w;
                *(float4*)(z40 + (size_t)rr * NC + (c0 - NC)) = o;
            }
        }
    }
}

// ---------------- conv2 aggregation + fused final-BN stats ----------------
// No early returns (syncthreads); per-block LDS stats -> banked global atomic.

__global__ __launch_bounds__(256) void agg40_add_bf16(const unsigned short* __restrict__ T,
                                                      const float* __restrict__ Z,
                                                      const int* __restrict__ csr,
                                                      const int* __restrict__ row_ptr,
                                                      const float* __restrict__ inv_cnt,
                                                      float* __restrict__ out,
                                                      float* __restrict__ sums2) {
    __shared__ float ls[80];
    int tid = threadIdx.x;
    if (tid < 80) ls[tid] = 0.f;
    __syncthreads();

    int lane = tid & 63;
    int wave = tid >> 6;
    int sub = lane / 20;
    int sl = lane % 20;
    int n = blockIdx.x * 12 + wave * 3 + sub;
    bool act = (lane < 60) && (n < NN);

    if (act) {
        int s = row_ptr[n], e = row_ptr[n + 1];
        const unsigned short* Tf = T + sl * 2;
        float a0 = 0.f, a1 = 0.f;
        int i = s;
        for (; i + 4 <= e; i += 4) {
            int s0 = csr[i], s1 = csr[i + 1], s2 = csr[i + 2], s3 = csr[i + 3];
            unsigned u0 = *(const unsigned*)(Tf + (size_t)s0 * NC);
            unsigned u1 = *(const unsigned*)(Tf + (size_t)s1 * NC);
            unsigned u2 = *(const unsigned*)(Tf + (size_t)s2 * NC);
            unsigned u3 = *(const unsigned*)(Tf + (size_t)s3 * NC);
            a0 += b2f_lo(u0) + b2f_lo(u1) + b2f_lo(u2) + b2f_lo(u3);
            a1 += b2f_hi(u0) + b2f_hi(u1) + b2f_hi(u2) + b2f_hi(u3);
        }
        for (; i < e; ++i) {
            unsigned u = *(const unsigned*)(Tf + (size_t)csr[i] * NC);
            a0 += b2f_lo(u);
            a1 += b2f_hi(u);
        }
        float ic = inv_cnt[n];
        const float2 zv = *(const float2*)(Z + (size_t)n * NC + sl * 2);
        float ox = a0 * ic + zv.x;
        float oy = a1 * ic + zv.y;
        float2 o; o.x = ox; o.y = oy;
        *(float2*)(out + (size_t)n * NC + sl * 2) = o;
        atomicAdd(&ls[2 * sl + 0], ox);
        atomicAdd(&ls[2 * sl + 1], oy);
        atomicAdd(&ls[NC + 2 * sl + 0], ox * ox);
        atomicAdd(&ls[NC + 2 * sl + 1], oy * oy);
    }
    __syncthreads();
    if (tid < 80) atomicAdd(&sums2[(blockIdx.x & (NBANK2 - 1)) * 80 + tid], ls[tid]);
}

// ---------------- final BN coefficients + apply ----------------

__global__ __launch_bounds__(64) void bn2_coef_kernel(const float* __restrict__ sums2,
                                                      const float* __restrict__ g,
                                                      const float* __restrict__ be,
                                                      float* __restrict__ sc,
                                                      float* __restrict__ sh) {
    int c = threadIdx.x;
    if (c >= NC) return;
    float s = 0.f, q = 0.f;
    for (int b = 0; b < NBANK2; ++b) {
        s += sums2[b * 80 + c];
        q += sums2[b * 80 + NC + c];
    }
    float invN = 1.0f / (float)NN;
    float mu = s * invN;
    float var = q * invN - mu * mu;
    float scv = rsqrtf(var + BN_EPS) * g[c];
    sc[c] = scv;
    sh[c] = be[c] - mu * scv;
}

__global__ __launch_bounds__(256) void bn2_apply_kernel(float* __restrict__ X,
                                                        const float* __restrict__ sc,
                                                        const float* __restrict__ sh) {
    size_t idx = (size_t)blockIdx.x * blockDim.x + threadIdx.x;
    if (idx >= (size_t)NN * NC) return;
    int c = (int)(idx % NC);
    X[idx] = X[idx] * sc[c] + sh[c];
}

// ---------------- launch ----------------

extern "C" void kernel_launch(void* const* d_in, const int* in_sizes, int n_in,
                              void* d_out, int out_size, void* d_ws, size_t ws_size,
                              hipStream_t stream) {
    const float* x   = (const float*)d_in[0];
    const int*   ei  = (const int*)d_in[1];
    const int*   srcv = ei;
    const int*   dstv = ei + NE;
    const float* W1l = (const float*)d_in[2];
    const float* b1  = (const float*)d_in[3];
    const float* W1r = (const float*)d_in[4];
    const float* Wxl = (const float*)d_in[5];
    const float* bx  = (const float*)d_in[6];
    const float* Wxr = (const float*)d_in[7];
    const float* W2l = (const float*)d_in[8];
    const float* b2  = (const float*)d_in[9];
    const float* W2r = (const float*)d_in[10];
    const float* g3  = (const float*)d_in[11];
    const float* be3 = (const float*)d_in[12];
    const float* g2  = (const float*)d_in[13];
    const float* be2 = (const float*)d_in[14];
    float* out = (float*)d_out;

    // workspace carve (16B aligned)
    char* w = (char*)d_ws;
    unsigned short* xb   = (unsigned short*)w; w += (size_t)NN * NF * 2;   // 25.6 MB
    unsigned short* h1b  = (unsigned short*)w; w += (size_t)NN * NF * 2;   // 25.6 MB
    unsigned short* aggb = (unsigned short*)w; w += (size_t)NN * NF * 2;   // 25.6 MB
    unsigned short* h2b  = (unsigned short*)w; w += (size_t)NN * NF * 2;   // 25.6 MB
    int* csr     = (int*)w; w += (size_t)NE * 4;                           // 6.4 MB
    int* row_ptr = (int*)w; w += (size_t)(NN + 4) * 4;
    float* inv_cnt = (float*)w; w += (size_t)NN * 4;
    float* bnbuf3  = (float*)w; w += (size_t)SBANK * 256 * 4;              // 32 KB banked
    float* sums2   = (float*)w; w += (size_t)NBANK2 * 80 * 4;              // 20 KB banked
    float* bnsc    = (float*)w; w += NF * 4;
    float* bnsh    = (float*)w; w += NF * 4;
    float* sc2     = (float*)w; w += 64 * 4;
    float* sh2     = (float*)w; w += 64 * 4;
    unsigned short* Bp1 = (unsigned short*)w; w += (size_t)256 * NF * 2;   // 64 KB
    unsigned short* Bpx = (unsigned short*)w; w += (size_t)256 * NF * 2;   // 64 KB
    unsigned short* Bp2 = (unsigned short*)w; w += (size_t)128 * 80 * 2;   // 20 KB
    int* bhist = (int*)w; w += NB * 4;
    int* bbase = (int*)w; w += NB * 4;
    int* bcurA = (int*)w; w += NB * 4;
    // overlays
    int2* stage = (int2*)h2b;        // 12.8 MB, dead until convx writes h2b
    unsigned short* t40 = xb;        // dead after conv1
    float* z40 = (float*)h1b;        // dead after convx

    // ---- zeroing ----
    hipMemsetAsync(bhist, 0, NB * 4, stream);
    hipMemsetAsync(bnbuf3, 0, (size_t)SBANK * 256 * 4, stream);
    hipMemsetAsync(sums2, 0, (size_t)NBANK2 * 80 * 4, stream);

    // ---- CSR build: bucket partition + merged deg/scan/fill ----
    bhist_kernel<<<PT_GRID, 256, 0, stream>>>(dstv, bhist);
    bscan_kernel<<<1, 256, 0, stream>>>(bhist, bbase, bcurA);
    part_kernel<<<PT_GRID, 256, 0, stream>>>(srcv, dstv, bcurA, stage);
    bucket_build_kernel<<<NBU, 512, 0, stream>>>((const long long*)stage, bbase, bcurA,
                                                 row_ptr, inv_cnt, csr);

    // ---- prep: x -> bf16; pack weights ----
    f2b4_kernel<<<(NN * NF / 4 + 255) / 256, 256, 0, stream>>>(x, xb, NN * NF / 4);
    pack_w_kernel<<<64, 64, 0, stream>>>(W1l, W1r, Bp1);
    pack_w_kernel<<<64, 64, 0, stream>>>(Wxl, Wxr, Bpx);
    pack_w80_kernel<<<20, 64, 0, stream>>>(W2l, W2r, Bp2);

    const int nblk_agg = (NN + 15) / 16;   // 6250

    // ---- conv1: h1 = relu([mean(x)|x] @ Bp1 + b1) -> h1b (bf16) ----
    agg_mean_bf16<<<nblk_agg, 256, 0, stream>>>(xb, csr, row_ptr, inv_cnt, aggb);
    lin_conv1_kernel<<<LIN_BLKS, 512, 0, stream>>>(aggb, xb, Bp1, b1, h1b);

    // ---- convx: h2 = [mean(h1)|h1] @ Bpx + bx -> h2b (bf16) + fused BN3 stats ----
    agg_mean_bf16<<<nblk_agg, 256, 0, stream>>>(h1b, csr, row_ptr, inv_cnt, aggb);
    lin_convx_kernel<<<LIN_BLKS, 512, 0, stream>>>(aggb, h1b, Bpx, bx, h2b, bnbuf3);

    // ---- BN3 coefficients; apply+relu fused into conv2 transform ----
    bn3_coef_kernel<<<1, 128, 0, stream>>>(bnbuf3, g3, be3, bnsc, bnsh);

    // ---- conv2 (transform-first, MFMA, BN3-apply fused on X-fragment) ----
    lin80_mfma_kernel<<<LIN80_GRID, 256, 0, stream>>>(h2b, Bp2, b2, bnsc, bnsh, t40, z40);
    agg40_add_bf16<<<(NN + 11) / 12, 256, 0, stream>>>(t40, z40, csr, row_ptr, inv_cnt, out, sums2);

    // ---- batch_norm2 (coef from fused stats, in-place apply) ----
    bn2_coef_kernel<<<1, 64, 0, stream>>>(sums2, g2, be2, sc2, sh2);
    bn2_apply_kernel<<<(NN * NC + 255) / 256, 256, 0, stream>>>(out, sc2, sh2);
}